// Round 11
// baseline (142.367 us; speedup 1.0000x reference)
//
#include <hip/hip_runtime.h>
#include <hip/hip_bf16.h>

#define N 8192
#define D 512

typedef __attribute__((ext_vector_type(8))) short short8;
typedef __attribute__((ext_vector_type(4))) float f32x4;

__device__ __forceinline__ float block_reduce_256(float v, float* red) {
    #pragma unroll
    for (int o = 1; o < 64; o <<= 1) v += __shfl_xor(v, o, 64);
    int w = threadIdx.x >> 6;
    if ((threadIdx.x & 63) == 0) red[w] = v;
    __syncthreads();
    float tot = red[0] + red[1] + red[2] + red[3];
    __syncthreads();
    return tot;
}

// Kernel 1: feature = row_normalize((qf-gf)^2)  [f32 to out, bf16 to ws], sq = rowsum(feature^2)
__global__ void feature_kernel(const float* __restrict__ qf, const float* __restrict__ gf,
                               float* __restrict__ feat, __hip_bfloat16* __restrict__ featb,
                               float* __restrict__ sq) {
    __shared__ float red[4];
    int row = blockIdx.x, t = threadIdx.x;
    const float2* q2 = (const float2*)(qf + (size_t)row * D);
    const float2* g2 = (const float2*)(gf + (size_t)row * D);
    float2 qv = q2[t], gv = g2[t];
    float a = qv.x - gv.x, b = qv.y - gv.y;
    float va = a * a, vb = b * b;
    float rs = block_reduce_256(va + vb, red);
    float inv = (rs == 0.0f) ? 0.0f : 1.0f / rs;
    float fa = va * inv, fb = vb * inv;
    ((float2*)(feat + (size_t)row * D))[t] = make_float2(fa, fb);
    __hip_bfloat162 h;
    h.x = __float2bfloat16(fa);
    h.y = __float2bfloat16(fb);
    ((__hip_bfloat162*)(featb + (size_t)row * D))[t] = h;
    float tot = block_reduce_256(fa * fa + fb * fb, red);
    if (t == 0) sq[row] = tot;
}

// Kernel 2: partial column sums of feature (64 blocks x 128 rows each)
__global__ void colsum_partial_kernel(const float* __restrict__ feat, float* __restrict__ partial) {
    int b = blockIdx.x, t = threadIdx.x;
    const float* fp = feat + (size_t)b * 128 * D;
    float a0 = 0.f, a1 = 0.f;
    for (int r = 0; r < 128; ++r) {
        a0 += fp[r * D + t];
        a1 += fp[r * D + t + 256];
    }
    partial[b * D + t] = a0;
    partial[b * D + t + 256] = a1;
}

// Kernel 3: finalize colsum c[512] and S = sum(sq)
__global__ void finalize_kernel(const float* __restrict__ partial, const float* __restrict__ sq,
                                float* __restrict__ cvec, float* __restrict__ Sval) {
    __shared__ float red[4];
    int t = threadIdx.x;
    if (blockIdx.x == 0) {
        float a0 = 0.f, a1 = 0.f;
        for (int b = 0; b < 64; ++b) {
            a0 += partial[b * D + t];
            a1 += partial[b * D + t + 256];
        }
        cvec[t] = a0;
        cvec[t + 256] = a1;
    } else {
        float s = 0.f;
        for (int k = 0; k < N / 256; ++k) s += sq[t + 256 * k];
        float tot = block_reduce_256(s, red);
        if (t == 0) Sval[0] = tot;
    }
}

// Kernel 4: rowinv_i = 1 / (N*sq_i + S - 2*dot(f_i, c) + 1)
__global__ void rowinv_kernel(const float* __restrict__ feat, const float* __restrict__ sq,
                              const float* __restrict__ cvec, const float* __restrict__ Sval,
                              float* __restrict__ rowinv) {
    __shared__ float red[4];
    int row = blockIdx.x, t = threadIdx.x;
    float2 f = ((const float2*)(feat + (size_t)row * D))[t];
    float2 c = ((const float2*)cvec)[t];
    float dot = block_reduce_256(f.x * c.x + f.y * c.y, red);
    if (t == 0) {
        float rs = (float)N * sq[row] + Sval[0] - 2.0f * dot + 1.0f;
        rowinv[row] = (rs == 0.0f) ? 0.0f : 1.0f / rs;
    }
}

// Kernel 5 ROUND-11: STRUCTURE change (all prior rounds sat at the reg-staged
// 2-phase ceiling ~580-650 TF; MFMA floor is 33 us, GEMM ran ~118 us).
// Counted-vmcnt deep pipeline (T3+T4) + global_load_lds + setprio (T5):
//   256^2 tile, 512 thr (8 waves 2x4), BK=32, TRIPLE-buffered LDS (96 KiB).
//   Prologue stages tiles 0..2. Each iter: s_waitcnt vmcnt(8) [2 tiles in
//   flight, never drains in main loop] -> raw s_barrier -> ds_read frags ->
//   setprio(1) 32 MFMA setprio(0) -> lgkmcnt(0) -> s_barrier -> stage tile
//   kt+3 into the just-freed buffer. Explicit waits cover every RAW/WAR
//   hazard (no reliance on compiler barrier drains; R1's race is addressed).
// Swizzle rule #21: LINEAR gload_lds dest + inverse-swizzled global source
// (c = c' ^ (r&3)) + swizzled ds_read (chunk = (lane>>4)^(lane&3)).
__global__ __launch_bounds__(512, 1) void adj_gemm_kernel(const __hip_bfloat16* __restrict__ featb,
                                                          const float* __restrict__ sq,
                                                          const float* __restrict__ rowinv,
                                                          float* __restrict__ out) {
    __shared__ __align__(16) char lds[98304];  // A: 3 x 16KB @0; B: 3 x 16KB @49152
    int wg = blockIdx.x;
    int id = (wg & 7) * 128 + (wg >> 3);  // XCD swizzle, bijective (1024 = 8*128)
    int bx = id & 31, by = id >> 5;
    int rowBase = by * 256, colBase = bx * 256;

    int t = threadIdx.x, lane = t & 63, w = t >> 6;
    int wr = w >> 2, wc = w & 3, g = lane >> 4;

    f32x4 acc[8][4];
    #pragma unroll
    for (int m = 0; m < 8; ++m)
        #pragma unroll
        for (int n = 0; n < 4; ++n) acc[m][n] = (f32x4){0.f, 0.f, 0.f, 0.f};

    // staging geometry: tile = [256 rows][32 k] bf16 = 1024 x 16B chunks.
    // wave-instr j in {0..15} covers chunks j*64 + lane; r = j*16 + (lane>>2),
    // LDS chunk col c' = lane&3; global source col c = c' ^ (r&3).
    int j0 = w * 2, j1 = w * 2 + 1;
    int rA0 = j0 * 16 + (lane >> 2), rA1 = j1 * 16 + (lane >> 2);
    int cc = lane & 3;
    int cg0 = cc ^ (rA0 & 3), cg1 = cc ^ (rA1 & 3);
    const __hip_bfloat16* gA0 = featb + (size_t)(rowBase + rA0) * D + cg0 * 8;
    const __hip_bfloat16* gA1 = featb + (size_t)(rowBase + rA1) * D + cg1 * 8;
    const __hip_bfloat16* gB0 = featb + (size_t)(colBase + rA0) * D + cg0 * 8;
    const __hip_bfloat16* gB1 = featb + (size_t)(colBase + rA1) * D + cg1 * 8;
    char* ldsA = lds;
    char* ldsB = lds + 49152;
    int dA0 = j0 * 1024, dA1 = j1 * 1024;  // wave-uniform dest bases (HW adds lane*16)

#define STAGE(p, kb) do { \
    __builtin_amdgcn_global_load_lds((const void*)(gA0 + (kb)), (void*)(ldsA + (p) * 16384 + dA0), 16, 0, 0); \
    __builtin_amdgcn_global_load_lds((const void*)(gA1 + (kb)), (void*)(ldsA + (p) * 16384 + dA1), 16, 0, 0); \
    __builtin_amdgcn_global_load_lds((const void*)(gB0 + (kb)), (void*)(ldsB + (p) * 16384 + dA0), 16, 0, 0); \
    __builtin_amdgcn_global_load_lds((const void*)(gB1 + (kb)), (void*)(ldsB + (p) * 16384 + dA1), 16, 0, 0); \
} while (0)

    STAGE(0, 0);
    STAGE(1, 32);
    STAGE(2, 64);

    int ca = ((g ^ (lane & 3)) << 4);       // swizzled 16B chunk within 64B row
    int arow0 = wr * 128 + (lane & 15);
    int brow0 = wc * 64 + (lane & 15);

    for (int kt = 0; kt < 16; ++kt) {
        if (kt <= 13)      asm volatile("s_waitcnt vmcnt(8)" ::: "memory");
        else if (kt == 14) asm volatile("s_waitcnt vmcnt(4)" ::: "memory");
        else               asm volatile("s_waitcnt vmcnt(0)" ::: "memory");
        __builtin_amdgcn_s_barrier();
        __builtin_amdgcn_sched_barrier(0);

        int p = kt % 3;
        const char* pA = ldsA + p * 16384;
        const char* pB = ldsB + p * 16384;
        short8 bf[4], af[8];
        #pragma unroll
        for (int n = 0; n < 4; ++n)
            bf[n] = *(const short8*)(pB + (brow0 + 16 * n) * 64 + ca);
        #pragma unroll
        for (int m = 0; m < 8; ++m)
            af[m] = *(const short8*)(pA + (arow0 + 16 * m) * 64 + ca);

        __builtin_amdgcn_s_setprio(1);
        #pragma unroll
        for (int m = 0; m < 8; ++m)
            #pragma unroll
            for (int n = 0; n < 4; ++n)
                acc[m][n] = __builtin_amdgcn_mfma_f32_16x16x32_bf16(af[m], bf[n], acc[m][n], 0, 0, 0);
        __builtin_amdgcn_s_setprio(0);

        asm volatile("s_waitcnt lgkmcnt(0)" ::: "memory");
        __builtin_amdgcn_sched_barrier(0);
        __builtin_amdgcn_s_barrier();
        __builtin_amdgcn_sched_barrier(0);

        if (kt < 13) STAGE(p, (kt + 3) * 32);
    }
#undef STAGE

    // epilogue: C/D layout col=lane&15 (j), row=g*4+reg (i); direct scalar stores
    float sqj[4];
    int jcol[4];
    #pragma unroll
    for (int n = 0; n < 4; ++n) {
        jcol[n] = colBase + wc * 64 + n * 16 + (lane & 15);
        sqj[n] = sq[jcol[n]];
    }
    #pragma unroll
    for (int m = 0; m < 8; ++m) {
        int ibase = rowBase + wr * 128 + m * 16 + g * 4;
        #pragma unroll
        for (int rI = 0; rI < 4; ++rI) {
            int i = ibase + rI;
            float si = sq[i], ri = rowinv[i];
            size_t ro = (size_t)i * N;
            #pragma unroll
            for (int n = 0; n < 4; ++n) {
                float pre = si + sqj[n] - 2.0f * acc[m][n][rI] + (i == jcol[n] ? 1.0f : 0.0f);
                out[ro + jcol[n]] = pre * ri;
            }
        }
    }
}

extern "C" void kernel_launch(void* const* d_in, const int* in_sizes, int n_in,
                              void* d_out, int out_size, void* d_ws, size_t ws_size,
                              hipStream_t stream) {
    const float* qf = (const float*)d_in[0];
    const float* gf = (const float*)d_in[1];
    float* out = (float*)d_out;
    float* feat = out + (size_t)N * N;  // feature output region

    // ws layout (~8.6 MB total)
    char* wsb = (char*)d_ws;
    __hip_bfloat16* featb = (__hip_bfloat16*)wsb;                          // 8 MB bf16 feature
    float* sq      = (float*)(wsb + 8388608);                              // 32 KB
    float* partial = (float*)(wsb + 8388608 + 32768);                      // 128 KB
    float* cvec    = (float*)(wsb + 8388608 + 32768 + 131072);             // 2 KB
    float* Sval    = (float*)(wsb + 8388608 + 32768 + 131072 + 2048);      // 4 B (+pad)
    float* rowinv  = (float*)(wsb + 8388608 + 32768 + 131072 + 2048 + 64); // 32 KB

    feature_kernel<<<N, 256, 0, stream>>>(qf, gf, feat, featb, sq);
    colsum_partial_kernel<<<64, 256, 0, stream>>>(feat, partial);
    finalize_kernel<<<2, 256, 0, stream>>>(partial, sq, cvec, Sval);
    rowinv_kernel<<<N, 256, 0, stream>>>(feat, sq, cvec, Sval, rowinv);
    adj_gemm_kernel<<<1024, 512, 0, stream>>>(featb, sq, rowinv, out);
}

// Round 12
// 124.936 us; speedup vs baseline: 1.1395x; 1.1395x over previous
//
#include <hip/hip_runtime.h>
#include <hip/hip_bf16.h>

#define N 8192
#define D 512

typedef __attribute__((ext_vector_type(8))) short short8;
typedef __attribute__((ext_vector_type(4))) float f32x4;

__device__ __forceinline__ float block_reduce_256(float v, float* red) {
    #pragma unroll
    for (int o = 1; o < 64; o <<= 1) v += __shfl_xor(v, o, 64);
    int w = threadIdx.x >> 6;
    if ((threadIdx.x & 63) == 0) red[w] = v;
    __syncthreads();
    float tot = red[0] + red[1] + red[2] + red[3];
    __syncthreads();
    return tot;
}

// Kernel 1: feature = row_normalize((qf-gf)^2)  [f32 to out, bf16 to ws], sq = rowsum(feature^2)
__global__ void feature_kernel(const float* __restrict__ qf, const float* __restrict__ gf,
                               float* __restrict__ feat, __hip_bfloat16* __restrict__ featb,
                               float* __restrict__ sq) {
    __shared__ float red[4];
    int row = blockIdx.x, t = threadIdx.x;
    const float2* q2 = (const float2*)(qf + (size_t)row * D);
    const float2* g2 = (const float2*)(gf + (size_t)row * D);
    float2 qv = q2[t], gv = g2[t];
    float a = qv.x - gv.x, b = qv.y - gv.y;
    float va = a * a, vb = b * b;
    float rs = block_reduce_256(va + vb, red);
    float inv = (rs == 0.0f) ? 0.0f : 1.0f / rs;
    float fa = va * inv, fb = vb * inv;
    ((float2*)(feat + (size_t)row * D))[t] = make_float2(fa, fb);
    __hip_bfloat162 h;
    h.x = __float2bfloat16(fa);
    h.y = __float2bfloat16(fb);
    ((__hip_bfloat162*)(featb + (size_t)row * D))[t] = h;
    float tot = block_reduce_256(fa * fa + fb * fb, red);
    if (t == 0) sq[row] = tot;
}

// Kernel 2: partial column sums of feature (64 blocks x 128 rows each)
__global__ void colsum_partial_kernel(const float* __restrict__ feat, float* __restrict__ partial) {
    int b = blockIdx.x, t = threadIdx.x;
    const float* fp = feat + (size_t)b * 128 * D;
    float a0 = 0.f, a1 = 0.f;
    for (int r = 0; r < 128; ++r) {
        a0 += fp[r * D + t];
        a1 += fp[r * D + t + 256];
    }
    partial[b * D + t] = a0;
    partial[b * D + t + 256] = a1;
}

// Kernel 3: finalize colsum c[512] and S = sum(sq)
__global__ void finalize_kernel(const float* __restrict__ partial, const float* __restrict__ sq,
                                float* __restrict__ cvec, float* __restrict__ Sval) {
    __shared__ float red[4];
    int t = threadIdx.x;
    if (blockIdx.x == 0) {
        float a0 = 0.f, a1 = 0.f;
        for (int b = 0; b < 64; ++b) {
            a0 += partial[b * D + t];
            a1 += partial[b * D + t + 256];
        }
        cvec[t] = a0;
        cvec[t + 256] = a1;
    } else {
        float s = 0.f;
        for (int k = 0; k < N / 256; ++k) s += sq[t + 256 * k];
        float tot = block_reduce_256(s, red);
        if (t == 0) Sval[0] = tot;
    }
}

// Kernel 4: rowinv_i = 1 / (N*sq_i + S - 2*dot(f_i, c) + 1)
__global__ void rowinv_kernel(const float* __restrict__ feat, const float* __restrict__ sq,
                              const float* __restrict__ cvec, const float* __restrict__ Sval,
                              float* __restrict__ rowinv) {
    __shared__ float red[4];
    int row = blockIdx.x, t = threadIdx.x;
    float2 f = ((const float2*)(feat + (size_t)row * D))[t];
    float2 c = ((const float2*)cvec)[t];
    float dot = block_reduce_256(f.x * c.x + f.y * c.y, red);
    if (t == 0) {
        float rs = (float)N * sq[row] + Sval[0] - 2.0f * dot + 1.0f;
        rowinv[row] = (rs == 0.0f) ? 0.0f : 1.0f / rs;
    }
}

// Kernel 5 ROUND-12: R3's high-occupancy body + symmetry + reg-direct mirror.
// Evidence fit (R3..R11): GEMM is READ-LATENCY-bound; aggregate read BW tracks
// waves/CU (R3: 16KB LDS, 3 blk/CU, 12 waves/CU -> 33 ns/tile; all 8-waves/CU
// variants -> 53-124 ns/tile). So: 128^2 tile, BK=32, SINGLE-buffer 16KB LDS,
// no prefetch (TLP hides latency), triangular by<=bx grid (2080 blocks),
// A-panel-sharing decode + XCD chunking, and the mirror tile written directly
// from registers as float4 (acc rI-dim = 4 consecutive i) -- no LDS transpose,
// no extra barriers, no occupancy loss.
__global__ __launch_bounds__(256, 3) void adj_gemm_sym_kernel(const __hip_bfloat16* __restrict__ featb,
                                                              const float* __restrict__ sq,
                                                              const float* __restrict__ rowinv,
                                                              float* __restrict__ out) {
    __shared__ __align__(16) char lds[16384];  // A [128][32]bf16 @0, B @8192
    int wg = blockIdx.x;
    int id = (wg & 7) * 260 + (wg >> 3);  // XCD chunking, 2080 = 8*260 (bijective)
    // by-major triangular decode: o(r) = r*(129-r)/2; consecutive id -> same by
    int r = (int)((129.0f - sqrtf(16641.0f - 8.0f * (float)id)) * 0.5f);
    if (r > 63) r = 63;
    while (r > 0 && (r * (129 - r)) / 2 > id) --r;
    while (((r + 1) * (128 - r)) / 2 <= id) ++r;
    int by = r;
    int bx = r + (id - (r * (129 - r)) / 2);
    int rowBase = by * 128, colBase = bx * 128;

    int t = threadIdx.x, lane = t & 63, w = t >> 6;
    int wr = w >> 1, wc = w & 1, g = lane >> 4;

    f32x4 acc[4][4];
    #pragma unroll
    for (int m = 0; m < 4; ++m)
        #pragma unroll
        for (int n = 0; n < 4; ++n) acc[m][n] = (f32x4){0.f, 0.f, 0.f, 0.f};

    // staging (R3-proven): thread t -> rows r0 = t>>2 and r0+64, 16B chunk cc = t&3
    int r0 = t >> 2, cc = t & 3;
    int s0 = (r0 >> 1) & 3;
    int woff = r0 * 64 + ((cc ^ s0) * 16);  // swizzle s(r)=(r>>1)&3; s(r0)==s(r0+64)
    const __hip_bfloat16* gA0 = featb + (size_t)(rowBase + r0) * D + cc * 8;
    const __hip_bfloat16* gB0 = featb + (size_t)(colBase + r0) * D + cc * 8;
    char* ldsA = lds;
    char* ldsB = lds + 8192;

    for (int ks = 0; ks < D / 32; ++ks) {
        int k0 = ks * 32;
        short8 vA0 = *(const short8*)(gA0 + k0);
        short8 vA1 = *(const short8*)(gA0 + 64 * D + k0);
        short8 vB0 = *(const short8*)(gB0 + k0);
        short8 vB1 = *(const short8*)(gB0 + 64 * D + k0);
        *(short8*)(ldsA + woff)        = vA0;
        *(short8*)(ldsA + woff + 4096) = vA1;
        *(short8*)(ldsB + woff)        = vB0;
        *(short8*)(ldsB + woff + 4096) = vB1;
        __syncthreads();

        short8 afrag[4], bfrag[4];
        #pragma unroll
        for (int m = 0; m < 4; ++m) {
            int rr = wr * 64 + m * 16 + (lane & 15);
            int c16 = (lane >> 4) ^ ((rr >> 1) & 3);
            afrag[m] = *(const short8*)(ldsA + rr * 64 + c16 * 16);
        }
        #pragma unroll
        for (int n = 0; n < 4; ++n) {
            int rr = wc * 64 + n * 16 + (lane & 15);
            int c16 = (lane >> 4) ^ ((rr >> 1) & 3);
            bfrag[n] = *(const short8*)(ldsB + rr * 64 + c16 * 16);
        }
        #pragma unroll
        for (int m = 0; m < 4; ++m)
            #pragma unroll
            for (int n = 0; n < 4; ++n)
                acc[m][n] = __builtin_amdgcn_mfma_f32_16x16x32_bf16(afrag[m], bfrag[n], acc[m][n], 0, 0, 0);
        __syncthreads();
    }

    // epilogue: C/D layout col=lane&15 (j), row=g*4+rI (i).
    // Direct: out[i][j] = pre * rowinv[i] (scalar, 64B row-segments).
    // Mirror (off-diag only): out[j][i0..i0+3] = pre * rowinv[j] (float4).
    float sqj[4], rj4[4];
    int jcol[4];
    #pragma unroll
    for (int n = 0; n < 4; ++n) {
        jcol[n] = colBase + wc * 64 + n * 16 + (lane & 15);
        sqj[n] = sq[jcol[n]];
        rj4[n] = rowinv[jcol[n]];
    }
    int offdiag = (by != bx);
    #pragma unroll
    for (int m = 0; m < 4; ++m) {
        int i0 = rowBase + wr * 64 + m * 16 + g * 4;
        float si0 = sq[i0], si1 = sq[i0 + 1], si2 = sq[i0 + 2], si3 = sq[i0 + 3];
        float ri0 = rowinv[i0], ri1 = rowinv[i0 + 1], ri2 = rowinv[i0 + 2], ri3 = rowinv[i0 + 3];
        #pragma unroll
        for (int n = 0; n < 4; ++n) {
            int j = jcol[n];
            float pre0 = si0 + sqj[n] - 2.0f * acc[m][n][0] + (i0 == j ? 1.0f : 0.0f);
            float pre1 = si1 + sqj[n] - 2.0f * acc[m][n][1] + (i0 + 1 == j ? 1.0f : 0.0f);
            float pre2 = si2 + sqj[n] - 2.0f * acc[m][n][2] + (i0 + 2 == j ? 1.0f : 0.0f);
            float pre3 = si3 + sqj[n] - 2.0f * acc[m][n][3] + (i0 + 3 == j ? 1.0f : 0.0f);
            out[(size_t)(i0 + 0) * N + j] = pre0 * ri0;
            out[(size_t)(i0 + 1) * N + j] = pre1 * ri1;
            out[(size_t)(i0 + 2) * N + j] = pre2 * ri2;
            out[(size_t)(i0 + 3) * N + j] = pre3 * ri3;
            if (offdiag) {
                f32x4 v;
                v[0] = pre0 * rj4[n];
                v[1] = pre1 * rj4[n];
                v[2] = pre2 * rj4[n];
                v[3] = pre3 * rj4[n];
                *(f32x4*)&out[(size_t)j * N + i0] = v;
            }
        }
    }
}

extern "C" void kernel_launch(void* const* d_in, const int* in_sizes, int n_in,
                              void* d_out, int out_size, void* d_ws, size_t ws_size,
                              hipStream_t stream) {
    const float* qf = (const float*)d_in[0];
    const float* gf = (const float*)d_in[1];
    float* out = (float*)d_out;
    float* feat = out + (size_t)N * N;  // feature output region

    // ws layout (~8.6 MB total)
    char* wsb = (char*)d_ws;
    __hip_bfloat16* featb = (__hip_bfloat16*)wsb;                          // 8 MB bf16 feature
    float* sq      = (float*)(wsb + 8388608);                              // 32 KB
    float* partial = (float*)(wsb + 8388608 + 32768);                      // 128 KB
    float* cvec    = (float*)(wsb + 8388608 + 32768 + 131072);             // 2 KB
    float* Sval    = (float*)(wsb + 8388608 + 32768 + 131072 + 2048);      // 4 B (+pad)
    float* rowinv  = (float*)(wsb + 8388608 + 32768 + 131072 + 2048 + 64); // 32 KB

    feature_kernel<<<N, 256, 0, stream>>>(qf, gf, feat, featb, sq);
    colsum_partial_kernel<<<64, 256, 0, stream>>>(feat, partial);
    finalize_kernel<<<2, 256, 0, stream>>>(partial, sq, cvec, Sval);
    rowinv_kernel<<<N, 256, 0, stream>>>(feat, sq, cvec, Sval, rowinv);
    adj_gemm_sym_kernel<<<2080, 256, 0, stream>>>(featb, sq, rowinv, out);
}